// Round 6
// baseline (3790.460 us; speedup 1.0000x reference)
//
#include <hip/hip_runtime.h>
#include <math.h>

#define B_ 8
#define N_ 4096
#define D_ 6
#define K_ 64
#define NS1_ 2048
#define NS2_ 512

typedef float v2f __attribute__((ext_vector_type(2)));

// ---------- helpers ----------

__device__ __forceinline__ float dist2_rn(const float* __restrict__ a, const float* __restrict__ q) {
    // exact np semantics: sequential sum of (a-b)^2, round-to-nearest each op, no fma
    float s = 0.f;
#pragma unroll
    for (int d = 0; d < 6; ++d) {
        float diff = __fsub_rn(a[d], q[d]);
        s = __fadd_rn(s, __fmul_rn(diff, diff));
    }
    return s;
}

__device__ __forceinline__ unsigned mapf(float x) {
    unsigned u = __float_as_uint(x);
    return (u & 0x80000000u) ? ~u : (u | 0x80000000u);
}
__device__ __forceinline__ float unmapf(unsigned u) {
    return __uint_as_float((u & 0x80000000u) ? (u & 0x7FFFFFFFu) : ~u);
}

// DPP move on a f64 key (two 32-bit DPPs); invalid lanes keep own value (identity for max).
template <int CTRL>
__device__ __forceinline__ double dppd(double k) {
    int lo = __double2loint(k), hi = __double2hiint(k);
    int nlo = __builtin_amdgcn_update_dpp(lo, lo, CTRL, 0xF, 0xF, false);
    int nhi = __builtin_amdgcn_update_dpp(hi, hi, CTRL, 0xF, 0xF, false);
    return __hiloint2double(nhi, nlo);
}

// ---------- flag sync (cross-block within one kernel; agent scope for XCD coherence) ----------

__device__ __forceinline__ void wait_flag(unsigned* f, int t) {
    if (t == 0) {
        while (__hip_atomic_load(f, __ATOMIC_RELAXED, __HIP_MEMORY_SCOPE_AGENT) == 0u)
            __builtin_amdgcn_s_sleep(32);
        __builtin_amdgcn_fence(__ATOMIC_ACQUIRE, "agent");
    }
    __syncthreads();
}

__device__ __forceinline__ void wait_count(unsigned* f, unsigned tgt, int t) {
    if (t == 0) {
        while (__hip_atomic_load(f, __ATOMIC_RELAXED, __HIP_MEMORY_SCOPE_AGENT) < tgt)
            __builtin_amdgcn_s_sleep(8);
        __builtin_amdgcn_fence(__ATOMIC_ACQUIRE, "agent");
    }
    __syncthreads();
}

__device__ __forceinline__ void release_add(unsigned* f, int t) {
    __syncthreads();  // drains vmcnt: all block stores/atomics done
    if (t == 0) {
        __threadfence();
        __hip_atomic_fetch_add(f, 1u, __ATOMIC_RELEASE, __HIP_MEMORY_SCOPE_AGENT);
    }
}

// ---------- FPS core (v9 arithmetic, verbatim): f64-fmax DPP ladder + vector update ----------

template <int NP, int NS>
__device__ __forceinline__ void fps_core(float* __restrict__ spos, int* __restrict__ sidx,
                                         double* __restrict__ part, int t) {
#pragma clang fp contract(off)
    constexpr int NT = 256;
    constexpr int P = NP / NT;
    constexpr int HP = P / 2;
    int lane = t & 63, w = t >> 6;

    // this thread's points in vector pairs: pair j = points t+NT*(2j), t+NT*(2j+1)
    v2f px2[HP][6];
#pragma unroll
    for (int j = 0; j < HP; ++j)
#pragma unroll
        for (int d = 0; d < 6; ++d) {
            px2[j][d].x = spos[(t + NT * (2 * j)) * 6 + d];
            px2[j][d].y = spos[(t + NT * (2 * j + 1)) * 6 + d];
        }

    // first sample = point 0
    float cx[6];
#pragma unroll
    for (int d = 0; d < 6; ++d) cx[d] = spos[d];

    v2f mind2[HP];
    float runv = -1.f;
    int runj = 0;
#pragma unroll
    for (int j = 0; j < HP; ++j) {
        v2f d2 = {0.f, 0.f};
#pragma unroll
        for (int d = 0; d < 6; ++d) {
            v2f df = px2[j][d] - cx[d];
            d2 = d2 + df * df;
        }
        mind2[j] = d2;
        if (d2.x > runv) { runv = d2.x; runj = t + NT * (2 * j); }      // ascending gidx:
        if (d2.y > runv) { runv = d2.y; runj = t + NT * (2 * j + 1); }  // strict > keeps lowest
    }

    for (int s = 1; s < NS; ++s) {
        // wave-level argmax reduce via f64-fmax DPP ladder on packed key
        double key = __hiloint2double((int)__float_as_uint(runv), (int)(unsigned)(~runj));
        key = fmax(key, dppd<0x111>(key));  // row_shr:1
        key = fmax(key, dppd<0x112>(key));  // row_shr:2
        key = fmax(key, dppd<0x114>(key));  // row_shr:4
        key = fmax(key, dppd<0x118>(key));  // row_shr:8
        key = fmax(key, dppd<0x142>(key));  // row_bcast:15
        key = fmax(key, dppd<0x143>(key));  // row_bcast:31 -> lane 63 = wave max
        if (lane == 63) part[(s & 1) * 4 + w] = key;
        __syncthreads();
        // every wave redundantly reduces the 4 partials (2 DPP levels, lanes 0..3)
        double kk = part[(s & 1) * 4 + (lane & 3)];
        kk = fmax(kk, dppd<0x111>(kk));
        kk = fmax(kk, dppd<0x112>(kk));   // lane 3 = max of partials 0..3
        int nx = ~__builtin_amdgcn_readlane(__double2loint(kk), 3);
        if (t == 0) sidx[s] = nx;  // off critical path; consumed only at the end

        // broadcast-read new center coords (nx uniform)
        const float2* sv2 = (const float2*)spos;
        float2 ca = sv2[nx * 3], cb = sv2[nx * 3 + 1], cc = sv2[nx * 3 + 2];
        cx[0] = ca.x; cx[1] = ca.y; cx[2] = cb.x; cx[3] = cb.y; cx[4] = cc.x; cx[5] = cc.y;

        // fused update (vector ops) + scalar min/argmax on components
        runv = -1.f;
        runj = 0;
#pragma unroll
        for (int j = 0; j < HP; ++j) {
            v2f d2 = {0.f, 0.f};
#pragma unroll
            for (int d = 0; d < 6; ++d) {
                v2f df = px2[j][d] - cx[d];
                d2 = d2 + df * df;
            }
            float mx = fminf(mind2[j].x, d2.x);
            float my = fminf(mind2[j].y, d2.y);
            mind2[j].x = mx;
            mind2[j].y = my;
            if (mx > runv) { runv = mx; runj = t + NT * (2 * j); }
            if (my > runv) { runv = my; runj = t + NT * (2 * j + 1); }
        }
    }
}

// ---------- ball scan (r9-proven semantics), point cloud staged in LDS ----------

template <int NPTS, int S>
__device__ __forceinline__ int ball_scan(const float* __restrict__ sp,
                                         const float* __restrict__ posq,
                                         float r2, int qid, int tid,
                                         float* __restrict__ sd, unsigned short* __restrict__ si) {
    float q[6];
#pragma unroll
    for (int d = 0; d < 6; ++d) q[d] = posq[(size_t)qid * 6 + d];

    int n = 0;
    float thr = INFINITY;
#pragma unroll 4
    for (int j = 0; j < NPTS; ++j) {
        float d2 = dist2_rn(sp + j * 6, q);
        if (d2 <= r2 && (n < K_ || d2 < thr)) {
            int i = (n < K_) ? n : (K_ - 1);
            if (n < K_) ++n;
            while (i > 0 && sd[(i - 1) * S + tid] > d2) {
                sd[i * S + tid] = sd[(i - 1) * S + tid];
                si[i * S + tid] = si[(i - 1) * S + tid];
                --i;
            }
            sd[i * S + tid] = d2;
            si[i * S + tid] = (unsigned short)j;
            if (n == K_) thr = sd[(K_ - 1) * S + tid];
        }
    }
    return n;
}

// ---------- sa2 per-query body (round-4/5 proven, verbatim) ----------

__device__ __forceinline__ void sa2_one(int qid, int lane,
        const float* __restrict__ pos1, const float* __restrict__ posq,
        const int* __restrict__ nbr, const int* __restrict__ cnt,
        const float* __restrict__ x1,
        const float* __restrict__ W1, const float* __restrict__ B1,
        const float* __restrict__ W2, const float* __restrict__ B2,
        const float* __restrict__ W3, const float* __restrict__ B3,
        float* __restrict__ out) {
    int b = qid / NS2_;
    float q[6];
#pragma unroll
    for (int d = 0; d < 6; ++d) q[d] = posq[(size_t)qid * 6 + d];
    int c = cnt[qid];
    float m0 = -INFINITY, m1 = -INFINITY, m2 = -INFINITY, m3 = -INFINITY;

    for (int n = 0; n < c; ++n) {
        int j = nbr[(size_t)qid * K_ + n];
        size_t row = (size_t)b * NS1_ + j;
        const float* xs = x1 + row * 128;
        float rel[6];
#pragma unroll
        for (int d = 0; d < 6; ++d) rel[d] = pos1[row * 6 + d] - q[d];
        float a0e = B1[lane], a0o = 0.f, a1e = B1[64 + lane], a1o = 0.f;
        for (int k = 0; k < 128; k += 2) {
            float v0 = xs[k], v1 = xs[k + 1];
            a0e = fmaf(W1[k * 128 + lane], v0, a0e);
            a1e = fmaf(W1[k * 128 + 64 + lane], v0, a1e);
            a0o = fmaf(W1[(k + 1) * 128 + lane], v1, a0o);
            a1o = fmaf(W1[(k + 1) * 128 + 64 + lane], v1, a1o);
        }
        float a0 = a0e + a0o, a1 = a1e + a1o;
#pragma unroll
        for (int d = 0; d < 6; ++d) {
            float v = rel[d];
            a0 = fmaf(W1[(128 + d) * 128 + lane], v, a0);
            a1 = fmaf(W1[(128 + d) * 128 + 64 + lane], v, a1);
        }
        float h1a = fmaxf(a0, 0.f), h1b = fmaxf(a1, 0.f);
        float c0 = B2[lane], c1 = B2[64 + lane];
        for (int k = 0; k < 64; ++k) {
            float v = __shfl(h1a, k, 64);
            c0 = fmaf(W2[k * 128 + lane], v, c0);
            c1 = fmaf(W2[k * 128 + 64 + lane], v, c1);
        }
        for (int k = 0; k < 64; ++k) {
            float v = __shfl(h1b, k, 64);
            c0 = fmaf(W2[(64 + k) * 128 + lane], v, c0);
            c1 = fmaf(W2[(64 + k) * 128 + 64 + lane], v, c1);
        }
        float h2a = fmaxf(c0, 0.f), h2b = fmaxf(c1, 0.f);
        float e0 = B3[lane], e1 = B3[64 + lane], e2 = B3[128 + lane], e3 = B3[192 + lane];
        for (int k = 0; k < 64; ++k) {
            float v = __shfl(h2a, k, 64);
            e0 = fmaf(W3[k * 256 + lane], v, e0);
            e1 = fmaf(W3[k * 256 + 64 + lane], v, e1);
            e2 = fmaf(W3[k * 256 + 128 + lane], v, e2);
            e3 = fmaf(W3[k * 256 + 192 + lane], v, e3);
        }
        for (int k = 0; k < 64; ++k) {
            float v = __shfl(h2b, k, 64);
            e0 = fmaf(W3[(64 + k) * 256 + lane], v, e0);
            e1 = fmaf(W3[(64 + k) * 256 + 64 + lane], v, e1);
            e2 = fmaf(W3[(64 + k) * 256 + 128 + lane], v, e2);
            e3 = fmaf(W3[(64 + k) * 256 + 192 + lane], v, e3);
        }
        m0 = fmaxf(m0, e0);
        m1 = fmaxf(m1, e1);
        m2 = fmaxf(m2, e2);
        m3 = fmaxf(m3, e3);
    }
    out[(size_t)qid * 256 + lane] = m0;
    out[(size_t)qid * 256 + 64 + lane] = m1;
    out[(size_t)qid * 256 + 128 + lane] = m2;
    out[(size_t)qid * 256 + 192 + lane] = m3;
}

// ---------- mlp3 per-wave 4-query body (round-1 proven, verbatim; x2 from global) ----------

__device__ __forceinline__ void mlp3_wave(int qid0, int lane,
        const float* __restrict__ x2, const float* __restrict__ pos2,
        const float* __restrict__ M0, const float* __restrict__ MB0,
        const float* __restrict__ M1, const float* __restrict__ MB1,
        const float* __restrict__ M2, const float* __restrict__ MB2,
        unsigned* __restrict__ g) {
    int b = qid0 >> 9;

    float xr[4][4];
#pragma unroll
    for (int q = 0; q < 4; ++q)
#pragma unroll
        for (int j = 0; j < 4; ++j) xr[q][j] = x2[(size_t)(qid0 + q) * 256 + j * 64 + lane];

    // L1: 262 -> 256, out channel = lane*4+u
    float a[4][4];
    {
        float4 bv = *(const float4*)&MB0[lane * 4];
#pragma unroll
        for (int q = 0; q < 4; ++q) { a[q][0] = bv.x; a[q][1] = bv.y; a[q][2] = bv.z; a[q][3] = bv.w; }
    }
#pragma unroll
    for (int j = 0; j < 4; ++j) {
        for (int k2 = 0; k2 < 64; ++k2) {
            int k = j * 64 + k2;
            float4 wv = *(const float4*)&M0[(size_t)k * 256 + lane * 4];
#pragma unroll
            for (int q = 0; q < 4; ++q) {
                float v = __shfl(xr[q][j], k2, 64);
                a[q][0] = fmaf(wv.x, v, a[q][0]);
                a[q][1] = fmaf(wv.y, v, a[q][1]);
                a[q][2] = fmaf(wv.z, v, a[q][2]);
                a[q][3] = fmaf(wv.w, v, a[q][3]);
            }
        }
    }
#pragma unroll
    for (int d = 0; d < 6; ++d) {
        float4 wv = *(const float4*)&M0[(size_t)(256 + d) * 256 + lane * 4];
#pragma unroll
        for (int q = 0; q < 4; ++q) {
            float v = pos2[(size_t)(qid0 + q) * 6 + d];
            a[q][0] = fmaf(wv.x, v, a[q][0]);
            a[q][1] = fmaf(wv.y, v, a[q][1]);
            a[q][2] = fmaf(wv.z, v, a[q][2]);
            a[q][3] = fmaf(wv.w, v, a[q][3]);
        }
    }
    float h1[4][4];
#pragma unroll
    for (int q = 0; q < 4; ++q)
#pragma unroll
        for (int u = 0; u < 4; ++u) h1[q][u] = fmaxf(a[q][u], 0.f);

    // L2: 256 -> 512, out channel = lane*8+u
    float c[4][8];
    {
        float4 b0 = *(const float4*)&MB1[lane * 8];
        float4 b1 = *(const float4*)&MB1[lane * 8 + 4];
#pragma unroll
        for (int q = 0; q < 4; ++q) {
            c[q][0] = b0.x; c[q][1] = b0.y; c[q][2] = b0.z; c[q][3] = b0.w;
            c[q][4] = b1.x; c[q][5] = b1.y; c[q][6] = b1.z; c[q][7] = b1.w;
        }
    }
    for (int l = 0; l < 64; ++l) {
#pragma unroll
        for (int r = 0; r < 4; ++r) {
            int k = l * 4 + r;
            float4 w0 = *(const float4*)&M1[(size_t)k * 512 + lane * 8];
            float4 w1 = *(const float4*)&M1[(size_t)k * 512 + lane * 8 + 4];
#pragma unroll
            for (int q = 0; q < 4; ++q) {
                float v = __shfl(h1[q][r], l, 64);
                c[q][0] = fmaf(w0.x, v, c[q][0]);
                c[q][1] = fmaf(w0.y, v, c[q][1]);
                c[q][2] = fmaf(w0.z, v, c[q][2]);
                c[q][3] = fmaf(w0.w, v, c[q][3]);
                c[q][4] = fmaf(w1.x, v, c[q][4]);
                c[q][5] = fmaf(w1.y, v, c[q][5]);
                c[q][6] = fmaf(w1.z, v, c[q][6]);
                c[q][7] = fmaf(w1.w, v, c[q][7]);
            }
        }
    }
    float h2[4][8];
#pragma unroll
    for (int q = 0; q < 4; ++q)
#pragma unroll
        for (int u = 0; u < 8; ++u) h2[q][u] = fmaxf(c[q][u], 0.f);

    // L3: 512 -> 1024, out channel = lane*16+u
    float e[4][16];
#pragma unroll
    for (int jj = 0; jj < 4; ++jj) {
        float4 bv = *(const float4*)&MB2[lane * 16 + jj * 4];
#pragma unroll
        for (int q = 0; q < 4; ++q) {
            e[q][jj * 4 + 0] = bv.x; e[q][jj * 4 + 1] = bv.y;
            e[q][jj * 4 + 2] = bv.z; e[q][jj * 4 + 3] = bv.w;
        }
    }
    for (int l = 0; l < 64; ++l) {
#pragma unroll
        for (int r = 0; r < 8; ++r) {
            int k = l * 8 + r;
            const float* wp = &M2[(size_t)k * 1024 + lane * 16];
            float4 w0 = *(const float4*)&wp[0];
            float4 w1 = *(const float4*)&wp[4];
            float4 w2 = *(const float4*)&wp[8];
            float4 w3 = *(const float4*)&wp[12];
#pragma unroll
            for (int q = 0; q < 4; ++q) {
                float v = __shfl(h2[q][r], l, 64);
                e[q][0]  = fmaf(w0.x, v, e[q][0]);
                e[q][1]  = fmaf(w0.y, v, e[q][1]);
                e[q][2]  = fmaf(w0.z, v, e[q][2]);
                e[q][3]  = fmaf(w0.w, v, e[q][3]);
                e[q][4]  = fmaf(w1.x, v, e[q][4]);
                e[q][5]  = fmaf(w1.y, v, e[q][5]);
                e[q][6]  = fmaf(w1.z, v, e[q][6]);
                e[q][7]  = fmaf(w1.w, v, e[q][7]);
                e[q][8]  = fmaf(w2.x, v, e[q][8]);
                e[q][9]  = fmaf(w2.y, v, e[q][9]);
                e[q][10] = fmaf(w2.z, v, e[q][10]);
                e[q][11] = fmaf(w2.w, v, e[q][11]);
                e[q][12] = fmaf(w3.x, v, e[q][12]);
                e[q][13] = fmaf(w3.y, v, e[q][13]);
                e[q][14] = fmaf(w3.z, v, e[q][14]);
                e[q][15] = fmaf(w3.w, v, e[q][15]);
            }
        }
    }
#pragma unroll
    for (int u = 0; u < 16; ++u) {
        float m = fmaxf(fmaxf(e[0][u], e[1][u]), fmaxf(e[2][u], e[3][u]));
        atomicMax(&g[b * 1024 + lane * 16 + u], mapf(m));
    }
}

// ---------- tail phases as noinline functions (register-allocation isolation) ----------

__device__ __attribute__((noinline)) void tail_sa2_mlp3(int b, int sub, int t,
        const float* pos1, const float* pos2,
        const int* nbr2, const int* cnt2, const float* x1, float* x2,
        const float* W2_0, const float* B2_0, const float* W2_1, const float* B2_1,
        const float* W2_2, const float* B2_2,
        const float* M0, const float* MB0, const float* M1, const float* MB1,
        const float* M2, const float* MB2, unsigned* g) {
    int lane = t & 63, w = t >> 6;
    int qbase = b * NS2_ + sub * 32;
    // sa2: 4 waves x 8 queries
    for (int i = 0; i < 8; ++i)
        sa2_one(qbase + w * 8 + i, lane, pos1, pos2, nbr2, cnt2, x1,
                W2_0, B2_0, W2_1, B2_1, W2_2, B2_2, x2);
    __syncthreads();  // drains vmcnt: block's x2 stores visible to block's loads
    // mlp3: 2 passes x (4 queries per wave)
    for (int p = 0; p < 2; ++p)
        mlp3_wave(qbase + p * 16 + w * 4, lane, x2, pos2, M0, MB0, M1, MB1, M2, MB2, g);
}

__device__ __attribute__((noinline)) void tail_mlp4(int b, int t,
        const unsigned* g, const float* W0, const float* B0,
        const float* W1, const float* B1, float* out) {
    __shared__ float h[512];
    // original bit-exact per-channel chains; 256 threads x 2 channels
    for (int ch = t; ch < 512; ch += 256) {
        float a = B0[ch];
        for (int k = 0; k < 1024; ++k) {
            float v = unmapf(g[b * 1024 + k]);
            a = fmaf(v, W0[k * 512 + ch], a);
        }
        h[ch] = fmaxf(a, 0.f);
    }
    __syncthreads();
    for (int ch = t; ch < 512; ch += 256) {
        float o = B1[ch];
        for (int k = 0; k < 512; ++k) o = fmaf(h[k], W1[k * 512 + ch], o);
        out[(size_t)b * 512 + ch] = o;
    }
}

// ---------- stage_all: the whole network in one co-resident kernel ----------
// blocks 0..7    : fps1 -> pos1+flag[b] -> (zero g) fps2 -> pos2+flag[8+b]
//                  -> prefetch W4 -> wait mlp3-count==16 -> mlp4 -> out
// blocks 8..135  : stage cloud -> wait pos1 -> ball1(128q) -> sa1 -> x1 + count[16+b]
//                  -> prefetch sa2/mlp3 weights (fps2 shadow) -> wait pos2, ball2-count, x1-count
//                  -> sa2(32q) -> mlp3(32q) -> atomicMax g -> count[32+b]
// blocks 136..199: wait pos1 -> stage pos1 -> wait pos2 -> ball2(64q) -> nbr2/cnt2 + count[24+b]
// Deadlock-free: every wait's releaser never waits on the waiter's later phases;
// x1-count bumped by each consumer BEFORE any wait; 200 blocks <= 256 CUs all co-resident.

__global__ __launch_bounds__(256, 1) void stage_all_kernel(
        const float* __restrict__ pos, float* __restrict__ pos1, float* __restrict__ pos2,
        float* __restrict__ x1, float* __restrict__ x2,
        int* __restrict__ nbr2, int* __restrict__ cnt2,
        unsigned* __restrict__ g, unsigned* flags, float* __restrict__ out,
        const float* __restrict__ W1_0, const float* __restrict__ B1_0,
        const float* __restrict__ W1_1, const float* __restrict__ B1_1,
        const float* __restrict__ W1_2, const float* __restrict__ B1_2,
        const float* __restrict__ W2_0, const float* __restrict__ B2_0,
        const float* __restrict__ W2_1, const float* __restrict__ B2_1,
        const float* __restrict__ W2_2, const float* __restrict__ B2_2,
        const float* __restrict__ M0, const float* __restrict__ MB0,
        const float* __restrict__ M1, const float* __restrict__ MB1,
        const float* __restrict__ M2, const float* __restrict__ MB2,
        const float* __restrict__ W4_0, const float* __restrict__ B4_0,
        const float* __restrict__ W4_1, const float* __restrict__ B4_1,
        float r2_1, float r2_2) {
    __shared__ union Smem {
        struct { float spos[N_ * 6]; int sidx[NS1_]; double part[8]; } fps;              // ~106.6 KB
        struct { float spos[N_ * 6]; float sd[K_ * 128]; unsigned short si[K_ * 128];
                 unsigned short scnt[128]; } p1;                                         // ~144.3 KB
        struct { float spos1[NS1_ * 6]; float sd2[K_ * 64]; unsigned short si2[K_ * 64]; } b2;  // 72 KB
    } sm;
    int t = threadIdx.x;
    int lane = t & 63, w = t >> 6;

    if (blockIdx.x < 8) {
        // ---------------- producer: fps1 -> fps2 -> mlp4 ----------------
        int b = blockIdx.x;
        float* spos = sm.fps.spos;
        int* sidx = sm.fps.sidx;
        double* part = sm.fps.part;

        {
            const float4* src = (const float4*)(pos + (size_t)b * N_ * 6);
            float4* dst = (float4*)spos;
            for (int e = t; e < N_ * 6 / 4; e += 256) dst[e] = src[e];
        }
        if (t == 0) sidx[0] = 0;
        __syncthreads();

        fps_core<N_, NS1_>(spos, sidx, part, t);
        __syncthreads();

        // phase A: gather sampled coords into registers (8 samples/thread)
        float smp[NS1_ / 256][6];
#pragma unroll
        for (int i = 0; i < NS1_ / 256; ++i) {
            int s = t + 256 * i;
            int ix = sidx[s];
#pragma unroll
            for (int d = 0; d < 6; ++d) smp[i][d] = spos[ix * 6 + d];
        }
#pragma unroll
        for (int i = 0; i < NS1_ / 256; ++i) {
            int s = t + 256 * i;
#pragma unroll
            for (int d = 0; d < 6; ++d) pos1[((size_t)b * NS1_ + s) * 6 + d] = smp[i][d];
        }
        __syncthreads();
        if (t == 0) {
            __threadfence();
            __hip_atomic_store(&flags[b], 1u, __ATOMIC_RELEASE, __HIP_MEMORY_SCOPE_AGENT);
        }

        // phase B: spos front = pos1 cloud; zero g for mlp3
#pragma unroll
        for (int i = 0; i < NS1_ / 256; ++i) {
            int s = t + 256 * i;
#pragma unroll
            for (int d = 0; d < 6; ++d) spos[s * 6 + d] = smp[i][d];
        }
        for (int e = t; e < 1024; e += 256) g[b * 1024 + e] = 0u;
        if (t == 0) sidx[0] = 0;
        __syncthreads();

        fps_core<NS1_, NS2_>(spos, sidx, part, t);
        __syncthreads();

        for (int s = t; s < NS2_; s += 256) {
            int ix = sidx[s];
#pragma unroll
            for (int d = 0; d < 6; ++d) pos2[((size_t)b * NS2_ + s) * 6 + d] = spos[ix * 6 + d];
        }
        __syncthreads();
        if (t == 0) {
            __threadfence();
            __hip_atomic_store(&flags[8 + b], 1u, __ATOMIC_RELEASE, __HIP_MEMORY_SCOPE_AGENT);
        }

        // prefetch mlp4 weights while consumers run (warms L2/L3; discarded)
        {
            float acc = 0.f;
            for (int e = t; e < 1024 * 512; e += 256) acc += W4_0[e];
            for (int e = t; e < 512 * 512; e += 256) acc += W4_1[e];
            asm volatile("" :: "v"(acc));
        }
        wait_count(&flags[32 + b], 16u, t);  // all mlp3 contributions to g[b] done
        tail_mlp4(b, t, g, W4_0, B4_0, W4_1, B4_1, out);
    } else if (blockIdx.x < 8 + 128) {
        // ---------------- consumer-A: ball1 -> sa1 -> sa2 -> mlp3 ----------------
        int blk = blockIdx.x - 8;
        int b = blk >> 4, sub = blk & 15;  // 16 blocks per cloud
        {
            const float4* src = (const float4*)(pos + (size_t)b * N_ * 6);
            float4* dst = (float4*)sm.p1.spos;
            for (int e = t; e < N_ * 6 / 4; e += 256) dst[e] = src[e];
        }
        __syncthreads();
        wait_flag(&flags[b], t);  // pos1 (queries) ready

        int qbase1 = b * NS1_ + sub * 128;
        if (t < 128) {
            int n = ball_scan<N_, 128>(sm.p1.spos, pos1, r2_1, qbase1 + t, t, sm.p1.sd, sm.p1.si);
            sm.p1.scnt[t] = (unsigned short)n;
        }
        __syncthreads();

        // sa1: 4 waves x 32 queries; neighbors + coords from LDS (hidden under fps2)
        for (int qq = 0; qq < 32; ++qq) {
            int lq = w * 32 + qq;
            int qid = qbase1 + lq;
            float q[6];
#pragma unroll
            for (int d = 0; d < 6; ++d) q[d] = pos1[(size_t)qid * 6 + d];
            int c = sm.p1.scnt[lq];
            float m0 = -INFINITY, m1 = -INFINITY;
            for (int n = 0; n < c; ++n) {
                int j = sm.p1.si[n * 128 + lq];
                float rel[6];
#pragma unroll
                for (int d = 0; d < 6; ++d) rel[d] = sm.p1.spos[j * 6 + d] - q[d];
                float a = B1_0[lane];
#pragma unroll
                for (int d = 0; d < 6; ++d) a = fmaf(W1_0[d * 64 + lane], rel[d], a);
                float h1 = fmaxf(a, 0.f);
                float a2 = B1_1[lane];
                for (int k = 0; k < 64; ++k) {
                    float v = __shfl(h1, k, 64);
                    a2 = fmaf(W1_1[k * 64 + lane], v, a2);
                }
                float h2 = fmaxf(a2, 0.f);
                float o0 = B1_2[lane], o1 = B1_2[64 + lane];
                for (int k = 0; k < 64; ++k) {
                    float v = __shfl(h2, k, 64);
                    o0 = fmaf(W1_2[k * 128 + lane], v, o0);
                    o1 = fmaf(W1_2[k * 128 + 64 + lane], v, o1);
                }
                m0 = fmaxf(m0, o0);
                m1 = fmaxf(m1, o1);
            }
            x1[(size_t)qid * 128 + lane] = m0;
            x1[(size_t)qid * 128 + 64 + lane] = m1;
        }
        release_add(&flags[16 + b], t);  // x1 slice published (bump BEFORE any wait)

        // prefetch sa2+mlp3 weights during fps2 shadow (warms L2/L3; discarded)
        {
            float acc = 0.f;
            for (int e = t; e < 134 * 128; e += 256) acc += W2_0[e];
            for (int e = t; e < 128 * 128; e += 256) acc += W2_1[e];
            for (int e = t; e < 128 * 256; e += 256) acc += W2_2[e];
            for (int e = t; e < 262 * 256; e += 256) acc += M0[e];
            for (int e = t; e < 256 * 512; e += 256) acc += M1[e];
            for (int e = t; e < 512 * 1024; e += 256) acc += M2[e];
            asm volatile("" :: "v"(acc));
        }

        wait_flag(&flags[8 + b], t);         // pos2 ready
        wait_count(&flags[24 + b], 8u, t);   // nbr2/cnt2 of cloud b ready
        wait_count(&flags[16 + b], 16u, t);  // all x1 of cloud b ready

        tail_sa2_mlp3(b, sub, t, pos1, pos2, nbr2, cnt2, x1, x2,
                      W2_0, B2_0, W2_1, B2_1, W2_2, B2_2,
                      M0, MB0, M1, MB1, M2, MB2, g);
        release_add(&flags[32 + b], t);  // mlp3 contributions for this block's 32 queries done
    } else {
        // ---------------- ball2: 64 queries/block, pos1 cloud staged in LDS ----------------
        int blk = blockIdx.x - 136;
        int b = blk >> 3;  // 8 blocks per cloud
        wait_flag(&flags[b], t);  // pos1 ready -> stage it (hidden under fps2)
        {
            const float4* src = (const float4*)(pos1 + (size_t)b * NS1_ * 6);
            float4* dst = (float4*)sm.b2.spos1;
            for (int e = t; e < NS1_ * 6 / 4; e += 256) dst[e] = src[e];
        }
        __syncthreads();
        wait_flag(&flags[8 + b], t);  // pos2 (queries) ready
        if (t < 64) {
            int qid = blk * 64 + t;
            int n = ball_scan<NS1_, 64>(sm.b2.spos1, pos2, r2_2, qid, t, sm.b2.sd2, sm.b2.si2);
            cnt2[qid] = n;
            for (int i = 0; i < n; ++i) nbr2[(size_t)qid * K_ + i] = (int)sm.b2.si2[i * 64 + t];
        }
        release_add(&flags[24 + b], t);  // nbr2/cnt2 published
    }
}

// ---------- launch ----------

extern "C" void kernel_launch(void* const* d_in, const int* in_sizes, int n_in,
                              void* d_out, int out_size, void* d_ws, size_t ws_size,
                              hipStream_t stream) {
    const float* pos = (const float*)d_in[0];  // [B*N, 6]
    const float* w1_0 = (const float*)d_in[3];
    const float* b1_0 = (const float*)d_in[4];
    const float* w1_1 = (const float*)d_in[5];
    const float* b1_1 = (const float*)d_in[6];
    const float* w1_2 = (const float*)d_in[7];
    const float* b1_2 = (const float*)d_in[8];
    const float* w2_0 = (const float*)d_in[9];
    const float* b2_0 = (const float*)d_in[10];
    const float* w2_1 = (const float*)d_in[11];
    const float* b2_1 = (const float*)d_in[12];
    const float* w2_2 = (const float*)d_in[13];
    const float* b2_2 = (const float*)d_in[14];
    const float* w3_0 = (const float*)d_in[15];
    const float* b3_0 = (const float*)d_in[16];
    const float* w3_1 = (const float*)d_in[17];
    const float* b3_1 = (const float*)d_in[18];
    const float* w3_2 = (const float*)d_in[19];
    const float* b3_2 = (const float*)d_in[20];
    const float* w4_0 = (const float*)d_in[21];
    const float* b4_0 = (const float*)d_in[22];
    const float* w4_1 = (const float*)d_in[23];
    const float* b4_1 = (const float*)d_in[24];
    float* out = (float*)d_out;

    char* ws = (char*)d_ws;
    size_t off = 0;
    float* pos1 = (float*)(ws + off);    off += (size_t)B_ * NS1_ * 6 * 4;
    float* pos2 = (float*)(ws + off);    off += (size_t)B_ * NS2_ * 6 * 4;
    float* x1 = (float*)(ws + off);      off += (size_t)B_ * NS1_ * 128 * 4;
    float* x2 = (float*)(ws + off);      off += (size_t)B_ * NS2_ * 256 * 4;
    int* nbr2 = (int*)(ws + off);        off += (size_t)B_ * NS2_ * K_ * 4;
    int* cnt2 = (int*)(ws + off);        off += (size_t)B_ * NS2_ * 4;
    unsigned* g = (unsigned*)(ws + off); off += (size_t)B_ * 1024 * 4;
    unsigned* flags = (unsigned*)(ws + off); off += 64 * 4;
    // flags: [0..7] pos1, [8..15] pos2, [16..23] x1-count(16),
    //        [24..31] ball2-count(8), [32..39] mlp3-count(16)

    const float r2_1 = (float)(0.2 * 0.2);
    const float r2_2 = (float)(0.4 * 0.4);

    hipMemsetAsync(flags, 0, 64 * 4, stream);

    // the whole network in one kernel
    stage_all_kernel<<<200, 256, 0, stream>>>(pos, pos1, pos2, x1, x2, nbr2, cnt2, g, flags, out,
                                              w1_0, b1_0, w1_1, b1_1, w1_2, b1_2,
                                              w2_0, b2_0, w2_1, b2_1, w2_2, b2_2,
                                              w3_0, b3_0, w3_1, b3_1, w3_2, b3_2,
                                              w4_0, b4_0, w4_1, b4_1,
                                              r2_1, r2_2);
}

// Round 7
// 2634.653 us; speedup vs baseline: 1.4387x; 1.4387x over previous
//
#include <hip/hip_runtime.h>
#include <math.h>

#define B_ 8
#define N_ 4096
#define D_ 6
#define K_ 64
#define NS1_ 2048
#define NS2_ 512

typedef float v2f __attribute__((ext_vector_type(2)));

// ---------- helpers ----------

__device__ __forceinline__ float dist2_rn(const float* __restrict__ a, const float* __restrict__ q) {
    // exact np semantics: sequential sum of (a-b)^2, round-to-nearest each op, no fma
    float s = 0.f;
#pragma unroll
    for (int d = 0; d < 6; ++d) {
        float diff = __fsub_rn(a[d], q[d]);
        s = __fadd_rn(s, __fmul_rn(diff, diff));
    }
    return s;
}

__device__ __forceinline__ unsigned mapf(float x) {
    unsigned u = __float_as_uint(x);
    return (u & 0x80000000u) ? ~u : (u | 0x80000000u);
}
__device__ __forceinline__ float unmapf(unsigned u) {
    return __uint_as_float((u & 0x80000000u) ? (u & 0x7FFFFFFFu) : ~u);
}

// DPP move on a f64 key (two 32-bit DPPs); invalid lanes keep own value (identity for max).
template <int CTRL>
__device__ __forceinline__ double dppd(double k) {
    int lo = __double2loint(k), hi = __double2hiint(k);
    int nlo = __builtin_amdgcn_update_dpp(lo, lo, CTRL, 0xF, 0xF, false);
    int nhi = __builtin_amdgcn_update_dpp(hi, hi, CTRL, 0xF, 0xF, false);
    return __hiloint2double(nhi, nlo);
}

// ---------- flag sync (cross-block within one kernel; agent scope for XCD coherence) ----------

__device__ __forceinline__ void wait_flag(unsigned* f, int t) {
    if (t == 0) {
        while (__hip_atomic_load(f, __ATOMIC_RELAXED, __HIP_MEMORY_SCOPE_AGENT) == 0u)
            __builtin_amdgcn_s_sleep(32);
        __builtin_amdgcn_fence(__ATOMIC_ACQUIRE, "agent");
    }
    __syncthreads();
}

// ---------- FPS core (v9 arithmetic, verbatim): f64-fmax DPP ladder + vector update ----------

template <int NP, int NS>
__device__ __forceinline__ void fps_core(float* __restrict__ spos, int* __restrict__ sidx,
                                         double* __restrict__ part, int t) {
#pragma clang fp contract(off)
    constexpr int NT = 256;
    constexpr int P = NP / NT;
    constexpr int HP = P / 2;
    int lane = t & 63, w = t >> 6;

    // this thread's points in vector pairs: pair j = points t+NT*(2j), t+NT*(2j+1)
    v2f px2[HP][6];
#pragma unroll
    for (int j = 0; j < HP; ++j)
#pragma unroll
        for (int d = 0; d < 6; ++d) {
            px2[j][d].x = spos[(t + NT * (2 * j)) * 6 + d];
            px2[j][d].y = spos[(t + NT * (2 * j + 1)) * 6 + d];
        }

    // first sample = point 0
    float cx[6];
#pragma unroll
    for (int d = 0; d < 6; ++d) cx[d] = spos[d];

    v2f mind2[HP];
    float runv = -1.f;
    int runj = 0;
#pragma unroll
    for (int j = 0; j < HP; ++j) {
        v2f d2 = {0.f, 0.f};
#pragma unroll
        for (int d = 0; d < 6; ++d) {
            v2f df = px2[j][d] - cx[d];
            d2 = d2 + df * df;
        }
        mind2[j] = d2;
        if (d2.x > runv) { runv = d2.x; runj = t + NT * (2 * j); }      // ascending gidx:
        if (d2.y > runv) { runv = d2.y; runj = t + NT * (2 * j + 1); }  // strict > keeps lowest
    }

    for (int s = 1; s < NS; ++s) {
        // wave-level argmax reduce via f64-fmax DPP ladder on packed key
        double key = __hiloint2double((int)__float_as_uint(runv), (int)(unsigned)(~runj));
        key = fmax(key, dppd<0x111>(key));  // row_shr:1
        key = fmax(key, dppd<0x112>(key));  // row_shr:2
        key = fmax(key, dppd<0x114>(key));  // row_shr:4
        key = fmax(key, dppd<0x118>(key));  // row_shr:8
        key = fmax(key, dppd<0x142>(key));  // row_bcast:15
        key = fmax(key, dppd<0x143>(key));  // row_bcast:31 -> lane 63 = wave max
        if (lane == 63) part[(s & 1) * 4 + w] = key;
        __syncthreads();
        // every wave redundantly reduces the 4 partials (2 DPP levels, lanes 0..3)
        double kk = part[(s & 1) * 4 + (lane & 3)];
        kk = fmax(kk, dppd<0x111>(kk));
        kk = fmax(kk, dppd<0x112>(kk));   // lane 3 = max of partials 0..3
        int nx = ~__builtin_amdgcn_readlane(__double2loint(kk), 3);
        if (t == 0) sidx[s] = nx;  // off critical path; consumed only at the end

        // broadcast-read new center coords (nx uniform)
        const float2* sv2 = (const float2*)spos;
        float2 ca = sv2[nx * 3], cb = sv2[nx * 3 + 1], cc = sv2[nx * 3 + 2];
        cx[0] = ca.x; cx[1] = ca.y; cx[2] = cb.x; cx[3] = cb.y; cx[4] = cc.x; cx[5] = cc.y;

        // fused update (vector ops) + scalar min/argmax on components
        runv = -1.f;
        runj = 0;
#pragma unroll
        for (int j = 0; j < HP; ++j) {
            v2f d2 = {0.f, 0.f};
#pragma unroll
            for (int d = 0; d < 6; ++d) {
                v2f df = px2[j][d] - cx[d];
                d2 = d2 + df * df;
            }
            float mx = fminf(mind2[j].x, d2.x);
            float my = fminf(mind2[j].y, d2.y);
            mind2[j].x = mx;
            mind2[j].y = my;
            if (mx > runv) { runv = mx; runj = t + NT * (2 * j); }
            if (my > runv) { runv = my; runj = t + NT * (2 * j + 1); }
        }
    }
}

// ---------- ball scan (r9-proven semantics), point cloud staged in LDS ----------

template <int NPTS, int S>
__device__ __forceinline__ int ball_scan(const float* __restrict__ sp,
                                         const float* __restrict__ posq,
                                         float r2, int qid, int tid,
                                         float* __restrict__ sd, unsigned short* __restrict__ si) {
    float q[6];
#pragma unroll
    for (int d = 0; d < 6; ++d) q[d] = posq[(size_t)qid * 6 + d];

    int n = 0;
    float thr = INFINITY;
#pragma unroll 4
    for (int j = 0; j < NPTS; ++j) {
        float d2 = dist2_rn(sp + j * 6, q);
        if (d2 <= r2 && (n < K_ || d2 < thr)) {
            int i = (n < K_) ? n : (K_ - 1);
            if (n < K_) ++n;
            while (i > 0 && sd[(i - 1) * S + tid] > d2) {
                sd[i * S + tid] = sd[(i - 1) * S + tid];
                si[i * S + tid] = si[(i - 1) * S + tid];
                --i;
            }
            sd[i * S + tid] = d2;
            si[i * S + tid] = (unsigned short)j;
            if (n == K_) thr = sd[(K_ - 1) * S + tid];
        }
    }
    return n;
}

// ---------- stage12: round-3/4 proven structure (UNCHANGED, 2005 us, no spill) ----------
// blocks 0..7    : fps1 -> pos1+flag[b] -> (zero g) fps2 -> pos2+flag[8+b]
// blocks 8..135  : ball1 (128 q) from LDS cloud -> sa1 in-LDS -> x1 (hidden under fps2)
// blocks 136..199: ball2 (64 q) from LDS-staged pos1 -> nbr2/cnt2 global
// sa2/mlp3 deliberately NOT here: co-compiling them with fps spills (rounds 2 & 6).

__global__ __launch_bounds__(256, 1) void stage12_kernel(
        const float* __restrict__ pos, float* __restrict__ pos1, float* __restrict__ pos2,
        float* __restrict__ x1, int* __restrict__ nbr2, int* __restrict__ cnt2,
        unsigned* __restrict__ g, unsigned* flags,
        const float* __restrict__ W1_0, const float* __restrict__ B1_0,
        const float* __restrict__ W1_1, const float* __restrict__ B1_1,
        const float* __restrict__ W1_2, const float* __restrict__ B1_2,
        float r2_1, float r2_2) {
    __shared__ union Smem {
        struct { float spos[N_ * 6]; int sidx[NS1_]; double part[8]; } fps;              // ~106.6 KB
        struct { float spos[N_ * 6]; float sd[K_ * 128]; unsigned short si[K_ * 128];
                 unsigned short scnt[128]; } p1;                                         // ~144.3 KB
        struct { float spos1[NS1_ * 6]; float sd2[K_ * 64]; unsigned short si2[K_ * 64]; } b2;  // 72 KB
    } sm;
    int t = threadIdx.x;
    int lane = t & 63, w = t >> 6;

    if (blockIdx.x < 8) {
        // ---------------- producer: fps1 -> fps2 ----------------
        int b = blockIdx.x;
        float* spos = sm.fps.spos;
        int* sidx = sm.fps.sidx;
        double* part = sm.fps.part;

        {
            const float4* src = (const float4*)(pos + (size_t)b * N_ * 6);
            float4* dst = (float4*)spos;
            for (int e = t; e < N_ * 6 / 4; e += 256) dst[e] = src[e];
        }
        if (t == 0) sidx[0] = 0;
        __syncthreads();

        fps_core<N_, NS1_>(spos, sidx, part, t);
        __syncthreads();

        // phase A: gather sampled coords into registers (8 samples/thread)
        float smp[NS1_ / 256][6];
#pragma unroll
        for (int i = 0; i < NS1_ / 256; ++i) {
            int s = t + 256 * i;
            int ix = sidx[s];
#pragma unroll
            for (int d = 0; d < 6; ++d) smp[i][d] = spos[ix * 6 + d];
        }
#pragma unroll
        for (int i = 0; i < NS1_ / 256; ++i) {
            int s = t + 256 * i;
#pragma unroll
            for (int d = 0; d < 6; ++d) pos1[((size_t)b * NS1_ + s) * 6 + d] = smp[i][d];
        }
        __syncthreads();
        if (t == 0) {
            __threadfence();
            __hip_atomic_store(&flags[b], 1u, __ATOMIC_RELEASE, __HIP_MEMORY_SCOPE_AGENT);
        }

        // phase B: spos front = pos1 cloud; zero g for mlp3
#pragma unroll
        for (int i = 0; i < NS1_ / 256; ++i) {
            int s = t + 256 * i;
#pragma unroll
            for (int d = 0; d < 6; ++d) spos[s * 6 + d] = smp[i][d];
        }
        for (int e = t; e < 1024; e += 256) g[b * 1024 + e] = 0u;
        if (t == 0) sidx[0] = 0;
        __syncthreads();

        fps_core<NS1_, NS2_>(spos, sidx, part, t);
        __syncthreads();

        for (int s = t; s < NS2_; s += 256) {
            int ix = sidx[s];
#pragma unroll
            for (int d = 0; d < 6; ++d) pos2[((size_t)b * NS2_ + s) * 6 + d] = spos[ix * 6 + d];
        }
        __syncthreads();
        if (t == 0) {
            __threadfence();
            __hip_atomic_store(&flags[8 + b], 1u, __ATOMIC_RELEASE, __HIP_MEMORY_SCOPE_AGENT);
        }
    } else if (blockIdx.x < 8 + 128) {
        // ---------------- ball1 + sa1: 128 queries/block ----------------
        int blk = blockIdx.x - 8;
        int b = blk >> 4;  // 16 blocks per cloud
        {
            const float4* src = (const float4*)(pos + (size_t)b * N_ * 6);
            float4* dst = (float4*)sm.p1.spos;
            for (int e = t; e < N_ * 6 / 4; e += 256) dst[e] = src[e];
        }
        __syncthreads();
        wait_flag(&flags[b], t);  // pos1 (queries) ready

        int qbase1 = b * NS1_ + (blk & 15) * 128;
        if (t < 128) {
            int n = ball_scan<N_, 128>(sm.p1.spos, pos1, r2_1, qbase1 + t, t, sm.p1.sd, sm.p1.si);
            sm.p1.scnt[t] = (unsigned short)n;
        }
        __syncthreads();

        // sa1: 4 waves x 32 queries; neighbors + coords from LDS (hidden under fps2)
        for (int qq = 0; qq < 32; ++qq) {
            int lq = w * 32 + qq;
            int qid = qbase1 + lq;
            float q[6];
#pragma unroll
            for (int d = 0; d < 6; ++d) q[d] = pos1[(size_t)qid * 6 + d];
            int c = sm.p1.scnt[lq];
            float m0 = -INFINITY, m1 = -INFINITY;
            for (int n = 0; n < c; ++n) {
                int j = sm.p1.si[n * 128 + lq];
                float rel[6];
#pragma unroll
                for (int d = 0; d < 6; ++d) rel[d] = sm.p1.spos[j * 6 + d] - q[d];
                float a = B1_0[lane];
#pragma unroll
                for (int d = 0; d < 6; ++d) a = fmaf(W1_0[d * 64 + lane], rel[d], a);
                float h1 = fmaxf(a, 0.f);
                float a2 = B1_1[lane];
                for (int k = 0; k < 64; ++k) {
                    float v = __shfl(h1, k, 64);
                    a2 = fmaf(W1_1[k * 64 + lane], v, a2);
                }
                float h2 = fmaxf(a2, 0.f);
                float o0 = B1_2[lane], o1 = B1_2[64 + lane];
                for (int k = 0; k < 64; ++k) {
                    float v = __shfl(h2, k, 64);
                    o0 = fmaf(W1_2[k * 128 + lane], v, o0);
                    o1 = fmaf(W1_2[k * 128 + 64 + lane], v, o1);
                }
                m0 = fmaxf(m0, o0);
                m1 = fmaxf(m1, o1);
            }
            x1[(size_t)qid * 128 + lane] = m0;
            x1[(size_t)qid * 128 + 64 + lane] = m1;
        }
    } else {
        // ---------------- ball2: 64 queries/block, pos1 cloud staged in LDS ----------------
        int blk = blockIdx.x - 136;
        int b = blk >> 3;  // 8 blocks per cloud
        wait_flag(&flags[b], t);  // pos1 ready -> stage it (hidden under fps2)
        {
            const float4* src = (const float4*)(pos1 + (size_t)b * NS1_ * 6);
            float4* dst = (float4*)sm.b2.spos1;
            for (int e = t; e < NS1_ * 6 / 4; e += 256) dst[e] = src[e];
        }
        __syncthreads();
        wait_flag(&flags[8 + b], t);  // pos2 (queries) ready
        if (t < 64) {
            int qid = blk * 64 + t;
            int n = ball_scan<NS1_, 64>(sm.b2.spos1, pos2, r2_2, qid, t, sm.b2.sd2, sm.b2.si2);
            cnt2[qid] = n;
            for (int i = 0; i < n; ++i) nbr2[(size_t)qid * K_ + i] = (int)sm.b2.si2[i * 64 + t];
        }
    }
}

// ---------- tail: sa2 + mlp3 + mlp4 in ONE kernel (round-4 bodies, all inline) ----------
// 256 blocks x 16 queries. After each block's atomicMax into g, it bumps done[b];
// the 32nd (last) block of each cloud acquires and runs the bit-exact mlp4 chains.

__global__ __launch_bounds__(256, 1) void tail_kernel(
        const float* __restrict__ pos1, const float* __restrict__ pos2,
        const int* __restrict__ nbr, const int* __restrict__ cnt,
        const float* __restrict__ x1,
        const float* __restrict__ W1, const float* __restrict__ B1,
        const float* __restrict__ W2, const float* __restrict__ B2,
        const float* __restrict__ W3, const float* __restrict__ B3,
        const float* __restrict__ M0, const float* __restrict__ MB0,
        const float* __restrict__ M1, const float* __restrict__ MB1,
        const float* __restrict__ M2, const float* __restrict__ MB2,
        const float* __restrict__ W4_0, const float* __restrict__ B4_0,
        const float* __restrict__ W4_1, const float* __restrict__ B4_1,
        unsigned* __restrict__ g, unsigned* done, float* __restrict__ out) {
    __shared__ float sx2[16 * 256];
    __shared__ float h4[512];
    __shared__ unsigned slast;
    int t = threadIdx.x;
    int lane = t & 63;
    int w = t >> 6;
    int qbase = blockIdx.x * 16;         // 16 level-2 queries per block
    int b = qbase >> 9;                  // 512 queries per cloud

    // ---- sa2: 4 waves x 4 queries (round-4 body verbatim); x2 -> LDS ----
    for (int qq = 0; qq < 4; ++qq) {
        int lq = w * 4 + qq;
        int qid = qbase + lq;
        float q[6];
#pragma unroll
        for (int d = 0; d < 6; ++d) q[d] = pos2[(size_t)qid * 6 + d];
        int c = cnt[qid];
        float m0 = -INFINITY, m1 = -INFINITY, m2 = -INFINITY, m3 = -INFINITY;
        for (int n = 0; n < c; ++n) {
            int j = nbr[(size_t)qid * K_ + n];
            size_t row = (size_t)b * NS1_ + j;
            const float* xs = x1 + row * 128;
            float rel[6];
#pragma unroll
            for (int d = 0; d < 6; ++d) rel[d] = pos1[row * 6 + d] - q[d];
            float a0e = B1[lane], a0o = 0.f, a1e = B1[64 + lane], a1o = 0.f;
            for (int k = 0; k < 128; k += 2) {
                float v0 = xs[k], v1 = xs[k + 1];
                a0e = fmaf(W1[k * 128 + lane], v0, a0e);
                a1e = fmaf(W1[k * 128 + 64 + lane], v0, a1e);
                a0o = fmaf(W1[(k + 1) * 128 + lane], v1, a0o);
                a1o = fmaf(W1[(k + 1) * 128 + 64 + lane], v1, a1o);
            }
            float a0 = a0e + a0o, a1 = a1e + a1o;
#pragma unroll
            for (int d = 0; d < 6; ++d) {
                float v = rel[d];
                a0 = fmaf(W1[(128 + d) * 128 + lane], v, a0);
                a1 = fmaf(W1[(128 + d) * 128 + 64 + lane], v, a1);
            }
            float h1a = fmaxf(a0, 0.f), h1b = fmaxf(a1, 0.f);
            float c0 = B2[lane], c1 = B2[64 + lane];
            for (int k = 0; k < 64; ++k) {
                float v = __shfl(h1a, k, 64);
                c0 = fmaf(W2[k * 128 + lane], v, c0);
                c1 = fmaf(W2[k * 128 + 64 + lane], v, c1);
            }
            for (int k = 0; k < 64; ++k) {
                float v = __shfl(h1b, k, 64);
                c0 = fmaf(W2[(64 + k) * 128 + lane], v, c0);
                c1 = fmaf(W2[(64 + k) * 128 + 64 + lane], v, c1);
            }
            float h2a = fmaxf(c0, 0.f), h2b = fmaxf(c1, 0.f);
            float e0 = B3[lane], e1 = B3[64 + lane], e2 = B3[128 + lane], e3 = B3[192 + lane];
            for (int k = 0; k < 64; ++k) {
                float v = __shfl(h2a, k, 64);
                e0 = fmaf(W3[k * 256 + lane], v, e0);
                e1 = fmaf(W3[k * 256 + 64 + lane], v, e1);
                e2 = fmaf(W3[k * 256 + 128 + lane], v, e2);
                e3 = fmaf(W3[k * 256 + 192 + lane], v, e3);
            }
            for (int k = 0; k < 64; ++k) {
                float v = __shfl(h2b, k, 64);
                e0 = fmaf(W3[(64 + k) * 256 + lane], v, e0);
                e1 = fmaf(W3[(64 + k) * 256 + 64 + lane], v, e1);
                e2 = fmaf(W3[(64 + k) * 256 + 128 + lane], v, e2);
                e3 = fmaf(W3[(64 + k) * 256 + 192 + lane], v, e3);
            }
            m0 = fmaxf(m0, e0);
            m1 = fmaxf(m1, e1);
            m2 = fmaxf(m2, e2);
            m3 = fmaxf(m3, e3);
        }
        sx2[lq * 256 + lane] = m0;
        sx2[lq * 256 + 64 + lane] = m1;
        sx2[lq * 256 + 128 + lane] = m2;
        sx2[lq * 256 + 192 + lane] = m3;
    }
    __syncthreads();

    // ---- mlp3 (round-1 body verbatim): wave = 4 queries, x2 from LDS ----
    {
        int lq0 = w * 4;
        int qid0 = qbase + lq0;

        float xr[4][4];
#pragma unroll
        for (int q = 0; q < 4; ++q)
#pragma unroll
            for (int j = 0; j < 4; ++j) xr[q][j] = sx2[(lq0 + q) * 256 + j * 64 + lane];

        // L1: 262 -> 256, out channel = lane*4+u
        float a[4][4];
        {
            float4 bv = *(const float4*)&MB0[lane * 4];
#pragma unroll
            for (int q = 0; q < 4; ++q) { a[q][0] = bv.x; a[q][1] = bv.y; a[q][2] = bv.z; a[q][3] = bv.w; }
        }
#pragma unroll
        for (int j = 0; j < 4; ++j) {
            for (int k2 = 0; k2 < 64; ++k2) {
                int k = j * 64 + k2;
                float4 wv = *(const float4*)&M0[(size_t)k * 256 + lane * 4];
#pragma unroll
                for (int q = 0; q < 4; ++q) {
                    float v = __shfl(xr[q][j], k2, 64);
                    a[q][0] = fmaf(wv.x, v, a[q][0]);
                    a[q][1] = fmaf(wv.y, v, a[q][1]);
                    a[q][2] = fmaf(wv.z, v, a[q][2]);
                    a[q][3] = fmaf(wv.w, v, a[q][3]);
                }
            }
        }
#pragma unroll
        for (int d = 0; d < 6; ++d) {
            float4 wv = *(const float4*)&M0[(size_t)(256 + d) * 256 + lane * 4];
#pragma unroll
            for (int q = 0; q < 4; ++q) {
                float v = pos2[(size_t)(qid0 + q) * 6 + d];
                a[q][0] = fmaf(wv.x, v, a[q][0]);
                a[q][1] = fmaf(wv.y, v, a[q][1]);
                a[q][2] = fmaf(wv.z, v, a[q][2]);
                a[q][3] = fmaf(wv.w, v, a[q][3]);
            }
        }
        float h1[4][4];
#pragma unroll
        for (int q = 0; q < 4; ++q)
#pragma unroll
            for (int u = 0; u < 4; ++u) h1[q][u] = fmaxf(a[q][u], 0.f);

        // L2: 256 -> 512, out channel = lane*8+u
        float c[4][8];
        {
            float4 b0 = *(const float4*)&MB1[lane * 8];
            float4 b1 = *(const float4*)&MB1[lane * 8 + 4];
#pragma unroll
            for (int q = 0; q < 4; ++q) {
                c[q][0] = b0.x; c[q][1] = b0.y; c[q][2] = b0.z; c[q][3] = b0.w;
                c[q][4] = b1.x; c[q][5] = b1.y; c[q][6] = b1.z; c[q][7] = b1.w;
            }
        }
        for (int l = 0; l < 64; ++l) {
#pragma unroll
            for (int r = 0; r < 4; ++r) {
                int k = l * 4 + r;
                float4 w0 = *(const float4*)&M1[(size_t)k * 512 + lane * 8];
                float4 w1 = *(const float4*)&M1[(size_t)k * 512 + lane * 8 + 4];
#pragma unroll
                for (int q = 0; q < 4; ++q) {
                    float v = __shfl(h1[q][r], l, 64);
                    c[q][0] = fmaf(w0.x, v, c[q][0]);
                    c[q][1] = fmaf(w0.y, v, c[q][1]);
                    c[q][2] = fmaf(w0.z, v, c[q][2]);
                    c[q][3] = fmaf(w0.w, v, c[q][3]);
                    c[q][4] = fmaf(w1.x, v, c[q][4]);
                    c[q][5] = fmaf(w1.y, v, c[q][5]);
                    c[q][6] = fmaf(w1.z, v, c[q][6]);
                    c[q][7] = fmaf(w1.w, v, c[q][7]);
                }
            }
        }
        float h2[4][8];
#pragma unroll
        for (int q = 0; q < 4; ++q)
#pragma unroll
            for (int u = 0; u < 8; ++u) h2[q][u] = fmaxf(c[q][u], 0.f);

        // L3: 512 -> 1024, out channel = lane*16+u
        float e[4][16];
#pragma unroll
        for (int jj = 0; jj < 4; ++jj) {
            float4 bv = *(const float4*)&MB2[lane * 16 + jj * 4];
#pragma unroll
            for (int q = 0; q < 4; ++q) {
                e[q][jj * 4 + 0] = bv.x; e[q][jj * 4 + 1] = bv.y;
                e[q][jj * 4 + 2] = bv.z; e[q][jj * 4 + 3] = bv.w;
            }
        }
        for (int l = 0; l < 64; ++l) {
#pragma unroll
            for (int r = 0; r < 8; ++r) {
                int k = l * 8 + r;
                const float* wp = &M2[(size_t)k * 1024 + lane * 16];
                float4 w0 = *(const float4*)&wp[0];
                float4 w1 = *(const float4*)&wp[4];
                float4 w2 = *(const float4*)&wp[8];
                float4 w3 = *(const float4*)&wp[12];
#pragma unroll
                for (int q = 0; q < 4; ++q) {
                    float v = __shfl(h2[q][r], l, 64);
                    e[q][0]  = fmaf(w0.x, v, e[q][0]);
                    e[q][1]  = fmaf(w0.y, v, e[q][1]);
                    e[q][2]  = fmaf(w0.z, v, e[q][2]);
                    e[q][3]  = fmaf(w0.w, v, e[q][3]);
                    e[q][4]  = fmaf(w1.x, v, e[q][4]);
                    e[q][5]  = fmaf(w1.y, v, e[q][5]);
                    e[q][6]  = fmaf(w1.z, v, e[q][6]);
                    e[q][7]  = fmaf(w1.w, v, e[q][7]);
                    e[q][8]  = fmaf(w2.x, v, e[q][8]);
                    e[q][9]  = fmaf(w2.y, v, e[q][9]);
                    e[q][10] = fmaf(w2.z, v, e[q][10]);
                    e[q][11] = fmaf(w2.w, v, e[q][11]);
                    e[q][12] = fmaf(w3.x, v, e[q][12]);
                    e[q][13] = fmaf(w3.y, v, e[q][13]);
                    e[q][14] = fmaf(w3.z, v, e[q][14]);
                    e[q][15] = fmaf(w3.w, v, e[q][15]);
                }
            }
        }
#pragma unroll
        for (int u = 0; u < 16; ++u) {
            float m = fmaxf(fmaxf(e[0][u], e[1][u]), fmaxf(e[2][u], e[3][u]));
            atomicMax(&g[b * 1024 + lane * 16 + u], mapf(m));
        }
    }

    // ---- completion: last block of cloud b runs mlp4 (in-kernel g read proven r6) ----
    __syncthreads();  // all atomicMax issued/drained for this block
    if (t == 0) {
        __threadfence();
        unsigned old = __hip_atomic_fetch_add(&done[b], 1u, __ATOMIC_ACQ_REL,
                                              __HIP_MEMORY_SCOPE_AGENT);
        slast = (old == 31u) ? 1u : 0u;
    }
    __syncthreads();
    if (slast) {
        if (t == 0) __builtin_amdgcn_fence(__ATOMIC_ACQUIRE, "agent");
        __syncthreads();
        // mlp4: bit-exact per-channel chains; 256 threads x 2 channels (round-6-passed mapping)
        for (int ch = t; ch < 512; ch += 256) {
            float a = B4_0[ch];
            for (int k = 0; k < 1024; ++k) {
                float v = unmapf(g[b * 1024 + k]);
                a = fmaf(v, W4_0[k * 512 + ch], a);
            }
            h4[ch] = fmaxf(a, 0.f);
        }
        __syncthreads();
        for (int ch = t; ch < 512; ch += 256) {
            float o = B4_1[ch];
            for (int k = 0; k < 512; ++k) o = fmaf(h4[k], W4_1[k * 512 + ch], o);
            out[(size_t)b * 512 + ch] = o;
        }
    }
}

// ---------- launch ----------

extern "C" void kernel_launch(void* const* d_in, const int* in_sizes, int n_in,
                              void* d_out, int out_size, void* d_ws, size_t ws_size,
                              hipStream_t stream) {
    const float* pos = (const float*)d_in[0];  // [B*N, 6]
    const float* w1_0 = (const float*)d_in[3];
    const float* b1_0 = (const float*)d_in[4];
    const float* w1_1 = (const float*)d_in[5];
    const float* b1_1 = (const float*)d_in[6];
    const float* w1_2 = (const float*)d_in[7];
    const float* b1_2 = (const float*)d_in[8];
    const float* w2_0 = (const float*)d_in[9];
    const float* b2_0 = (const float*)d_in[10];
    const float* w2_1 = (const float*)d_in[11];
    const float* b2_1 = (const float*)d_in[12];
    const float* w2_2 = (const float*)d_in[13];
    const float* b2_2 = (const float*)d_in[14];
    const float* w3_0 = (const float*)d_in[15];
    const float* b3_0 = (const float*)d_in[16];
    const float* w3_1 = (const float*)d_in[17];
    const float* b3_1 = (const float*)d_in[18];
    const float* w3_2 = (const float*)d_in[19];
    const float* b3_2 = (const float*)d_in[20];
    const float* w4_0 = (const float*)d_in[21];
    const float* b4_0 = (const float*)d_in[22];
    const float* w4_1 = (const float*)d_in[23];
    const float* b4_1 = (const float*)d_in[24];
    float* out = (float*)d_out;

    char* ws = (char*)d_ws;
    size_t off = 0;
    float* pos1 = (float*)(ws + off);    off += (size_t)B_ * NS1_ * 6 * 4;
    float* pos2 = (float*)(ws + off);    off += (size_t)B_ * NS2_ * 6 * 4;
    float* x1 = (float*)(ws + off);      off += (size_t)B_ * NS1_ * 128 * 4;
    int* nbr2 = (int*)(ws + off);        off += (size_t)B_ * NS2_ * K_ * 4;
    int* cnt2 = (int*)(ws + off);        off += (size_t)B_ * NS2_ * 4;
    unsigned* g = (unsigned*)(ws + off); off += (size_t)B_ * 1024 * 4;
    unsigned* flags = (unsigned*)(ws + off); off += 64 * 4;
    // flags[0..7]=pos1 ready, flags[8..15]=pos2 ready, flags[40..47]=tail done counters

    const float r2_1 = (float)(0.2 * 0.2);
    const float r2_2 = (float)(0.4 * 0.4);

    hipMemsetAsync(flags, 0, 64 * 4, stream);

    // 1. fps1 -> {ball1+sa1, fps2, ball2} overlapped (proven 2005 us)
    stage12_kernel<<<200, 256, 0, stream>>>(pos, pos1, pos2, x1, nbr2, cnt2, g, flags,
                                            w1_0, b1_0, w1_1, b1_1, w1_2, b1_2,
                                            r2_1, r2_2);
    // 2. entire tail in one dispatch: sa2 + mlp3 + (last-block-per-cloud) mlp4
    tail_kernel<<<(B_ * NS2_) / 16, 256, 0, stream>>>(pos1, pos2, nbr2, cnt2, x1,
                                                      w2_0, b2_0, w2_1, b2_1, w2_2, b2_2,
                                                      w3_0, b3_0, w3_1, b3_1, w3_2, b3_2,
                                                      w4_0, b4_0, w4_1, b4_1,
                                                      g, flags + 40, out);
}

// Round 8
// 2497.275 us; speedup vs baseline: 1.5178x; 1.0550x over previous
//
#include <hip/hip_runtime.h>
#include <math.h>

#define B_ 8
#define N_ 4096
#define D_ 6
#define K_ 64
#define NS1_ 2048
#define NS2_ 512

typedef float v2f __attribute__((ext_vector_type(2)));

// ---------- helpers ----------

__device__ __forceinline__ float dist2_rn(const float* __restrict__ a, const float* __restrict__ q) {
    // exact np semantics: sequential sum of (a-b)^2, round-to-nearest each op, no fma
    float s = 0.f;
#pragma unroll
    for (int d = 0; d < 6; ++d) {
        float diff = __fsub_rn(a[d], q[d]);
        s = __fadd_rn(s, __fmul_rn(diff, diff));
    }
    return s;
}

__device__ __forceinline__ unsigned mapf(float x) {
    unsigned u = __float_as_uint(x);
    return (u & 0x80000000u) ? ~u : (u | 0x80000000u);
}
__device__ __forceinline__ float unmapf(unsigned u) {
    return __uint_as_float((u & 0x80000000u) ? (u & 0x7FFFFFFFu) : ~u);
}

// DPP move on a f64 key (two 32-bit DPPs); invalid lanes keep own value (identity for max).
template <int CTRL>
__device__ __forceinline__ double dppd(double k) {
    int lo = __double2loint(k), hi = __double2hiint(k);
    int nlo = __builtin_amdgcn_update_dpp(lo, lo, CTRL, 0xF, 0xF, false);
    int nhi = __builtin_amdgcn_update_dpp(hi, hi, CTRL, 0xF, 0xF, false);
    return __hiloint2double(nhi, nlo);
}

// ---------- clock-keeper spin (DPM theory: hold gfx clocks up during the serial FPS) ----------

__device__ __forceinline__ void busy_fma(float s) {
    float a = s + 1.f, b = 1.0001f, c = 0.9999f, d = s + 2.f;
#pragma unroll 4
    for (int i = 0; i < 64; ++i) {
        a = fmaf(a, b, 1.f);
        b = fmaf(b, c, 1.f);
        c = fmaf(c, d, 1.f);
        d = fmaf(d, a, 1.f);
    }
    asm volatile("" :: "v"(a), "v"(b), "v"(c), "v"(d));
}

// ---------- flag sync (cross-block within one kernel; agent scope for XCD coherence) ----------
// busy-FMA poll (not s_sleep): parked waves look idle to the DPM governor.

__device__ __forceinline__ void wait_flag(unsigned* f, int t) {
    while (__hip_atomic_load(f, __ATOMIC_RELAXED, __HIP_MEMORY_SCOPE_AGENT) == 0u)
        busy_fma((float)t);
    __syncthreads();
    if (t == 0) __builtin_amdgcn_fence(__ATOMIC_ACQUIRE, "agent");
    __syncthreads();
}

// ---------- FPS core (v9 arithmetic, verbatim): f64-fmax DPP ladder + vector update ----------

template <int NP, int NS>
__device__ __forceinline__ void fps_core(float* __restrict__ spos, int* __restrict__ sidx,
                                         double* __restrict__ part, int t) {
#pragma clang fp contract(off)
    constexpr int NT = 256;
    constexpr int P = NP / NT;
    constexpr int HP = P / 2;
    int lane = t & 63, w = t >> 6;

    // this thread's points in vector pairs: pair j = points t+NT*(2j), t+NT*(2j+1)
    v2f px2[HP][6];
#pragma unroll
    for (int j = 0; j < HP; ++j)
#pragma unroll
        for (int d = 0; d < 6; ++d) {
            px2[j][d].x = spos[(t + NT * (2 * j)) * 6 + d];
            px2[j][d].y = spos[(t + NT * (2 * j + 1)) * 6 + d];
        }

    // first sample = point 0
    float cx[6];
#pragma unroll
    for (int d = 0; d < 6; ++d) cx[d] = spos[d];

    v2f mind2[HP];
    float runv = -1.f;
    int runj = 0;
#pragma unroll
    for (int j = 0; j < HP; ++j) {
        v2f d2 = {0.f, 0.f};
#pragma unroll
        for (int d = 0; d < 6; ++d) {
            v2f df = px2[j][d] - cx[d];
            d2 = d2 + df * df;
        }
        mind2[j] = d2;
        if (d2.x > runv) { runv = d2.x; runj = t + NT * (2 * j); }      // ascending gidx:
        if (d2.y > runv) { runv = d2.y; runj = t + NT * (2 * j + 1); }  // strict > keeps lowest
    }

    for (int s = 1; s < NS; ++s) {
        // wave-level argmax reduce via f64-fmax DPP ladder on packed key
        double key = __hiloint2double((int)__float_as_uint(runv), (int)(unsigned)(~runj));
        key = fmax(key, dppd<0x111>(key));  // row_shr:1
        key = fmax(key, dppd<0x112>(key));  // row_shr:2
        key = fmax(key, dppd<0x114>(key));  // row_shr:4
        key = fmax(key, dppd<0x118>(key));  // row_shr:8
        key = fmax(key, dppd<0x142>(key));  // row_bcast:15
        key = fmax(key, dppd<0x143>(key));  // row_bcast:31 -> lane 63 = wave max
        if (lane == 63) part[(s & 1) * 4 + w] = key;
        __syncthreads();
        // every wave redundantly reduces the 4 partials (2 DPP levels, lanes 0..3)
        double kk = part[(s & 1) * 4 + (lane & 3)];
        kk = fmax(kk, dppd<0x111>(kk));
        kk = fmax(kk, dppd<0x112>(kk));   // lane 3 = max of partials 0..3
        int nx = ~__builtin_amdgcn_readlane(__double2loint(kk), 3);
        if (t == 0) sidx[s] = nx;  // off critical path; consumed only at the end

        // broadcast-read new center coords (nx uniform)
        const float2* sv2 = (const float2*)spos;
        float2 ca = sv2[nx * 3], cb = sv2[nx * 3 + 1], cc = sv2[nx * 3 + 2];
        cx[0] = ca.x; cx[1] = ca.y; cx[2] = cb.x; cx[3] = cb.y; cx[4] = cc.x; cx[5] = cc.y;

        // fused update (vector ops) + scalar min/argmax on components
        runv = -1.f;
        runj = 0;
#pragma unroll
        for (int j = 0; j < HP; ++j) {
            v2f d2 = {0.f, 0.f};
#pragma unroll
            for (int d = 0; d < 6; ++d) {
                v2f df = px2[j][d] - cx[d];
                d2 = d2 + df * df;
            }
            float mx = fminf(mind2[j].x, d2.x);
            float my = fminf(mind2[j].y, d2.y);
            mind2[j].x = mx;
            mind2[j].y = my;
            if (mx > runv) { runv = mx; runj = t + NT * (2 * j); }
            if (my > runv) { runv = my; runj = t + NT * (2 * j + 1); }
        }
    }
}

// ---------- ball scan (r9-proven semantics), point cloud staged in LDS ----------

template <int NPTS, int S>
__device__ __forceinline__ int ball_scan(const float* __restrict__ sp,
                                         const float* __restrict__ posq,
                                         float r2, int qid, int tid,
                                         float* __restrict__ sd, unsigned short* __restrict__ si) {
    float q[6];
#pragma unroll
    for (int d = 0; d < 6; ++d) q[d] = posq[(size_t)qid * 6 + d];

    int n = 0;
    float thr = INFINITY;
#pragma unroll 4
    for (int j = 0; j < NPTS; ++j) {
        float d2 = dist2_rn(sp + j * 6, q);
        if (d2 <= r2 && (n < K_ || d2 < thr)) {
            int i = (n < K_) ? n : (K_ - 1);
            if (n < K_) ++n;
            while (i > 0 && sd[(i - 1) * S + tid] > d2) {
                sd[i * S + tid] = sd[(i - 1) * S + tid];
                si[i * S + tid] = si[(i - 1) * S + tid];
                --i;
            }
            sd[i * S + tid] = d2;
            si[i * S + tid] = (unsigned short)j;
            if (n == K_) thr = sd[(K_ - 1) * S + tid];
        }
    }
    return n;
}

// ---------- stage12: round-4 proven structure + clock-keeper blocks ----------
// blocks 0..7    : fps1 -> pos1+flag[b] -> (zero g) fps2 -> pos2+flag[8+b] -> bump done-count
// blocks 8..135  : ball1 (128 q) -> sa1 -> x1; then spin until producers done (hold clocks)
// blocks 136..199: ball2 (64 q) -> nbr2/cnt2
// blocks 200..255: dedicated clock-keeper spinners (FMA burn until producers done)
// All waits busy-FMA poll. 256 blocks <= 256 CUs, all co-resident; spinners wait only on
// producers, producers wait on nothing -> deadlock-free. No arithmetic changes (bit-exact).

__global__ __launch_bounds__(256, 1) void stage12_kernel(
        const float* __restrict__ pos, float* __restrict__ pos1, float* __restrict__ pos2,
        float* __restrict__ x1, int* __restrict__ nbr2, int* __restrict__ cnt2,
        unsigned* __restrict__ g, unsigned* flags,
        const float* __restrict__ W1_0, const float* __restrict__ B1_0,
        const float* __restrict__ W1_1, const float* __restrict__ B1_1,
        const float* __restrict__ W1_2, const float* __restrict__ B1_2,
        float r2_1, float r2_2) {
    __shared__ union Smem {
        struct { float spos[N_ * 6]; int sidx[NS1_]; double part[8]; } fps;              // ~106.6 KB
        struct { float spos[N_ * 6]; float sd[K_ * 128]; unsigned short si[K_ * 128];
                 unsigned short scnt[128]; } p1;                                         // ~144.3 KB
        struct { float spos1[NS1_ * 6]; float sd2[K_ * 64]; unsigned short si2[K_ * 64]; } b2;  // 72 KB
    } sm;
    int t = threadIdx.x;
    int lane = t & 63, w = t >> 6;

    if (blockIdx.x < 8) {
        // ---------------- producer: fps1 -> fps2 ----------------
        int b = blockIdx.x;
        float* spos = sm.fps.spos;
        int* sidx = sm.fps.sidx;
        double* part = sm.fps.part;

        {
            const float4* src = (const float4*)(pos + (size_t)b * N_ * 6);
            float4* dst = (float4*)spos;
            for (int e = t; e < N_ * 6 / 4; e += 256) dst[e] = src[e];
        }
        if (t == 0) sidx[0] = 0;
        __syncthreads();

        fps_core<N_, NS1_>(spos, sidx, part, t);
        __syncthreads();

        // phase A: gather sampled coords into registers (8 samples/thread)
        float smp[NS1_ / 256][6];
#pragma unroll
        for (int i = 0; i < NS1_ / 256; ++i) {
            int s = t + 256 * i;
            int ix = sidx[s];
#pragma unroll
            for (int d = 0; d < 6; ++d) smp[i][d] = spos[ix * 6 + d];
        }
#pragma unroll
        for (int i = 0; i < NS1_ / 256; ++i) {
            int s = t + 256 * i;
#pragma unroll
            for (int d = 0; d < 6; ++d) pos1[((size_t)b * NS1_ + s) * 6 + d] = smp[i][d];
        }
        __syncthreads();
        if (t == 0) {
            __threadfence();
            __hip_atomic_store(&flags[b], 1u, __ATOMIC_RELEASE, __HIP_MEMORY_SCOPE_AGENT);
        }

        // phase B: spos front = pos1 cloud; zero g for mlp3
#pragma unroll
        for (int i = 0; i < NS1_ / 256; ++i) {
            int s = t + 256 * i;
#pragma unroll
            for (int d = 0; d < 6; ++d) spos[s * 6 + d] = smp[i][d];
        }
        for (int e = t; e < 1024; e += 256) g[b * 1024 + e] = 0u;
        if (t == 0) sidx[0] = 0;
        __syncthreads();

        fps_core<NS1_, NS2_>(spos, sidx, part, t);
        __syncthreads();

        for (int s = t; s < NS2_; s += 256) {
            int ix = sidx[s];
#pragma unroll
            for (int d = 0; d < 6; ++d) pos2[((size_t)b * NS2_ + s) * 6 + d] = spos[ix * 6 + d];
        }
        __syncthreads();
        if (t == 0) {
            __threadfence();
            __hip_atomic_store(&flags[8 + b], 1u, __ATOMIC_RELEASE, __HIP_MEMORY_SCOPE_AGENT);
            __hip_atomic_fetch_add(&flags[48], 1u, __ATOMIC_RELAXED, __HIP_MEMORY_SCOPE_AGENT);
        }
    } else if (blockIdx.x < 8 + 128) {
        // ---------------- ball1 + sa1: 128 queries/block ----------------
        int blk = blockIdx.x - 8;
        int b = blk >> 4;  // 16 blocks per cloud
        {
            const float4* src = (const float4*)(pos + (size_t)b * N_ * 6);
            float4* dst = (float4*)sm.p1.spos;
            for (int e = t; e < N_ * 6 / 4; e += 256) dst[e] = src[e];
        }
        __syncthreads();
        wait_flag(&flags[b], t);  // pos1 (queries) ready (busy-FMA poll spans fps1)

        int qbase1 = b * NS1_ + (blk & 15) * 128;
        if (t < 128) {
            int n = ball_scan<N_, 128>(sm.p1.spos, pos1, r2_1, qbase1 + t, t, sm.p1.sd, sm.p1.si);
            sm.p1.scnt[t] = (unsigned short)n;
        }
        __syncthreads();

        // sa1: 4 waves x 32 queries; neighbors + coords from LDS (hidden under fps2)
        for (int qq = 0; qq < 32; ++qq) {
            int lq = w * 32 + qq;
            int qid = qbase1 + lq;
            float q[6];
#pragma unroll
            for (int d = 0; d < 6; ++d) q[d] = pos1[(size_t)qid * 6 + d];
            int c = sm.p1.scnt[lq];
            float m0 = -INFINITY, m1 = -INFINITY;
            for (int n = 0; n < c; ++n) {
                int j = sm.p1.si[n * 128 + lq];
                float rel[6];
#pragma unroll
                for (int d = 0; d < 6; ++d) rel[d] = sm.p1.spos[j * 6 + d] - q[d];
                float a = B1_0[lane];
#pragma unroll
                for (int d = 0; d < 6; ++d) a = fmaf(W1_0[d * 64 + lane], rel[d], a);
                float h1 = fmaxf(a, 0.f);
                float a2 = B1_1[lane];
                for (int k = 0; k < 64; ++k) {
                    float v = __shfl(h1, k, 64);
                    a2 = fmaf(W1_1[k * 64 + lane], v, a2);
                }
                float h2 = fmaxf(a2, 0.f);
                float o0 = B1_2[lane], o1 = B1_2[64 + lane];
                for (int k = 0; k < 64; ++k) {
                    float v = __shfl(h2, k, 64);
                    o0 = fmaf(W1_2[k * 128 + lane], v, o0);
                    o1 = fmaf(W1_2[k * 128 + 64 + lane], v, o1);
                }
                m0 = fmaxf(m0, o0);
                m1 = fmaxf(m1, o1);
            }
            x1[(size_t)qid * 128 + lane] = m0;
            x1[(size_t)qid * 128 + 64 + lane] = m1;
        }
        // keep this CU active until producers finish (clock-keeper role; no one waits on us)
        while (__hip_atomic_load(&flags[48], __ATOMIC_RELAXED, __HIP_MEMORY_SCOPE_AGENT) < 8u)
            busy_fma((float)t);
    } else if (blockIdx.x < 200) {
        // ---------------- ball2: 64 queries/block, pos1 cloud staged in LDS ----------------
        int blk = blockIdx.x - 136;
        int b = blk >> 3;  // 8 blocks per cloud
        wait_flag(&flags[b], t);  // pos1 ready -> stage it (hidden under fps2)
        {
            const float4* src = (const float4*)(pos1 + (size_t)b * NS1_ * 6);
            float4* dst = (float4*)sm.b2.spos1;
            for (int e = t; e < NS1_ * 6 / 4; e += 256) dst[e] = src[e];
        }
        __syncthreads();
        wait_flag(&flags[8 + b], t);  // pos2 (queries) ready (busy poll spans fps2)
        if (t < 64) {
            int qid = blk * 64 + t;
            int n = ball_scan<NS1_, 64>(sm.b2.spos1, pos2, r2_2, qid, t, sm.b2.sd2, sm.b2.si2);
            cnt2[qid] = n;
            for (int i = 0; i < n; ++i) nbr2[(size_t)qid * K_ + i] = (int)sm.b2.si2[i * 64 + t];
        }
    } else {
        // ---------------- dedicated clock-keeper spinners ----------------
        while (__hip_atomic_load(&flags[48], __ATOMIC_RELAXED, __HIP_MEMORY_SCOPE_AGENT) < 8u)
            busy_fma((float)(t + blockIdx.x));
    }
}

// ---------- sa2 + mlp3 fused: 16 queries/block (round-4 proven, UNCHANGED) ----------

__global__ __launch_bounds__(256, 1) void sa2_mlp3_kernel(
        const float* __restrict__ pos1, const float* __restrict__ pos2,
        const int* __restrict__ nbr, const int* __restrict__ cnt,
        const float* __restrict__ x1,
        const float* __restrict__ W1, const float* __restrict__ B1,
        const float* __restrict__ W2, const float* __restrict__ B2,
        const float* __restrict__ W3, const float* __restrict__ B3,
        const float* __restrict__ M0, const float* __restrict__ MB0,
        const float* __restrict__ M1, const float* __restrict__ MB1,
        const float* __restrict__ M2, const float* __restrict__ MB2,
        unsigned* __restrict__ g) {
    __shared__ float sx2[16 * 256];
    int lane = threadIdx.x & 63;
    int w = threadIdx.x >> 6;
    int qbase = blockIdx.x * 16;         // 16 level-2 queries per block
    int b = qbase >> 9;                  // 512 queries per cloud

    // ---- sa2: 4 waves x 4 queries; x2 -> LDS ----
    for (int qq = 0; qq < 4; ++qq) {
        int lq = w * 4 + qq;
        int qid = qbase + lq;
        float q[6];
#pragma unroll
        for (int d = 0; d < 6; ++d) q[d] = pos2[(size_t)qid * 6 + d];
        int c = cnt[qid];
        float m0 = -INFINITY, m1 = -INFINITY, m2 = -INFINITY, m3 = -INFINITY;
        for (int n = 0; n < c; ++n) {
            int j = nbr[(size_t)qid * K_ + n];
            size_t row = (size_t)b * NS1_ + j;
            const float* xs = x1 + row * 128;
            float rel[6];
#pragma unroll
            for (int d = 0; d < 6; ++d) rel[d] = pos1[row * 6 + d] - q[d];
            float a0e = B1[lane], a0o = 0.f, a1e = B1[64 + lane], a1o = 0.f;
            for (int k = 0; k < 128; k += 2) {
                float v0 = xs[k], v1 = xs[k + 1];
                a0e = fmaf(W1[k * 128 + lane], v0, a0e);
                a1e = fmaf(W1[k * 128 + 64 + lane], v0, a1e);
                a0o = fmaf(W1[(k + 1) * 128 + lane], v1, a0o);
                a1o = fmaf(W1[(k + 1) * 128 + 64 + lane], v1, a1o);
            }
            float a0 = a0e + a0o, a1 = a1e + a1o;
#pragma unroll
            for (int d = 0; d < 6; ++d) {
                float v = rel[d];
                a0 = fmaf(W1[(128 + d) * 128 + lane], v, a0);
                a1 = fmaf(W1[(128 + d) * 128 + 64 + lane], v, a1);
            }
            float h1a = fmaxf(a0, 0.f), h1b = fmaxf(a1, 0.f);
            float c0 = B2[lane], c1 = B2[64 + lane];
            for (int k = 0; k < 64; ++k) {
                float v = __shfl(h1a, k, 64);
                c0 = fmaf(W2[k * 128 + lane], v, c0);
                c1 = fmaf(W2[k * 128 + 64 + lane], v, c1);
            }
            for (int k = 0; k < 64; ++k) {
                float v = __shfl(h1b, k, 64);
                c0 = fmaf(W2[(64 + k) * 128 + lane], v, c0);
                c1 = fmaf(W2[(64 + k) * 128 + 64 + lane], v, c1);
            }
            float h2a = fmaxf(c0, 0.f), h2b = fmaxf(c1, 0.f);
            float e0 = B3[lane], e1 = B3[64 + lane], e2 = B3[128 + lane], e3 = B3[192 + lane];
            for (int k = 0; k < 64; ++k) {
                float v = __shfl(h2a, k, 64);
                e0 = fmaf(W3[k * 256 + lane], v, e0);
                e1 = fmaf(W3[k * 256 + 64 + lane], v, e1);
                e2 = fmaf(W3[k * 256 + 128 + lane], v, e2);
                e3 = fmaf(W3[k * 256 + 192 + lane], v, e3);
            }
            for (int k = 0; k < 64; ++k) {
                float v = __shfl(h2b, k, 64);
                e0 = fmaf(W3[(64 + k) * 256 + lane], v, e0);
                e1 = fmaf(W3[(64 + k) * 256 + 64 + lane], v, e1);
                e2 = fmaf(W3[(64 + k) * 256 + 128 + lane], v, e2);
                e3 = fmaf(W3[(64 + k) * 256 + 192 + lane], v, e3);
            }
            m0 = fmaxf(m0, e0);
            m1 = fmaxf(m1, e1);
            m2 = fmaxf(m2, e2);
            m3 = fmaxf(m3, e3);
        }
        sx2[lq * 256 + lane] = m0;
        sx2[lq * 256 + 64 + lane] = m1;
        sx2[lq * 256 + 128 + lane] = m2;
        sx2[lq * 256 + 192 + lane] = m3;
    }
    __syncthreads();

    // ---- mlp3 (round-1 body verbatim): wave = 4 queries, x2 from LDS ----
    int lq0 = w * 4;
    int qid0 = qbase + lq0;

    float xr[4][4];
#pragma unroll
    for (int q = 0; q < 4; ++q)
#pragma unroll
        for (int j = 0; j < 4; ++j) xr[q][j] = sx2[(lq0 + q) * 256 + j * 64 + lane];

    // L1: 262 -> 256, out channel = lane*4+u
    float a[4][4];
    {
        float4 bv = *(const float4*)&MB0[lane * 4];
#pragma unroll
        for (int q = 0; q < 4; ++q) { a[q][0] = bv.x; a[q][1] = bv.y; a[q][2] = bv.z; a[q][3] = bv.w; }
    }
#pragma unroll
    for (int j = 0; j < 4; ++j) {
        for (int k2 = 0; k2 < 64; ++k2) {
            int k = j * 64 + k2;
            float4 wv = *(const float4*)&M0[(size_t)k * 256 + lane * 4];
#pragma unroll
            for (int q = 0; q < 4; ++q) {
                float v = __shfl(xr[q][j], k2, 64);
                a[q][0] = fmaf(wv.x, v, a[q][0]);
                a[q][1] = fmaf(wv.y, v, a[q][1]);
                a[q][2] = fmaf(wv.z, v, a[q][2]);
                a[q][3] = fmaf(wv.w, v, a[q][3]);
            }
        }
    }
#pragma unroll
    for (int d = 0; d < 6; ++d) {
        float4 wv = *(const float4*)&M0[(size_t)(256 + d) * 256 + lane * 4];
#pragma unroll
        for (int q = 0; q < 4; ++q) {
            float v = pos2[(size_t)(qid0 + q) * 6 + d];
            a[q][0] = fmaf(wv.x, v, a[q][0]);
            a[q][1] = fmaf(wv.y, v, a[q][1]);
            a[q][2] = fmaf(wv.z, v, a[q][2]);
            a[q][3] = fmaf(wv.w, v, a[q][3]);
        }
    }
    float h1[4][4];
#pragma unroll
    for (int q = 0; q < 4; ++q)
#pragma unroll
        for (int u = 0; u < 4; ++u) h1[q][u] = fmaxf(a[q][u], 0.f);

    // L2: 256 -> 512, out channel = lane*8+u
    float c[4][8];
    {
        float4 b0 = *(const float4*)&MB1[lane * 8];
        float4 b1 = *(const float4*)&MB1[lane * 8 + 4];
#pragma unroll
        for (int q = 0; q < 4; ++q) {
            c[q][0] = b0.x; c[q][1] = b0.y; c[q][2] = b0.z; c[q][3] = b0.w;
            c[q][4] = b1.x; c[q][5] = b1.y; c[q][6] = b1.z; c[q][7] = b1.w;
        }
    }
    for (int l = 0; l < 64; ++l) {
#pragma unroll
        for (int r = 0; r < 4; ++r) {
            int k = l * 4 + r;
            float4 w0 = *(const float4*)&M1[(size_t)k * 512 + lane * 8];
            float4 w1 = *(const float4*)&M1[(size_t)k * 512 + lane * 8 + 4];
#pragma unroll
            for (int q = 0; q < 4; ++q) {
                float v = __shfl(h1[q][r], l, 64);
                c[q][0] = fmaf(w0.x, v, c[q][0]);
                c[q][1] = fmaf(w0.y, v, c[q][1]);
                c[q][2] = fmaf(w0.z, v, c[q][2]);
                c[q][3] = fmaf(w0.w, v, c[q][3]);
                c[q][4] = fmaf(w1.x, v, c[q][4]);
                c[q][5] = fmaf(w1.y, v, c[q][5]);
                c[q][6] = fmaf(w1.z, v, c[q][6]);
                c[q][7] = fmaf(w1.w, v, c[q][7]);
            }
        }
    }
    float h2[4][8];
#pragma unroll
    for (int q = 0; q < 4; ++q)
#pragma unroll
        for (int u = 0; u < 8; ++u) h2[q][u] = fmaxf(c[q][u], 0.f);

    // L3: 512 -> 1024, out channel = lane*16+u
    float e[4][16];
#pragma unroll
    for (int jj = 0; jj < 4; ++jj) {
        float4 bv = *(const float4*)&MB2[lane * 16 + jj * 4];
#pragma unroll
        for (int q = 0; q < 4; ++q) {
            e[q][jj * 4 + 0] = bv.x; e[q][jj * 4 + 1] = bv.y;
            e[q][jj * 4 + 2] = bv.z; e[q][jj * 4 + 3] = bv.w;
        }
    }
    for (int l = 0; l < 64; ++l) {
#pragma unroll
        for (int r = 0; r < 8; ++r) {
            int k = l * 8 + r;
            const float* wp = &M2[(size_t)k * 1024 + lane * 16];
            float4 w0 = *(const float4*)&wp[0];
            float4 w1 = *(const float4*)&wp[4];
            float4 w2 = *(const float4*)&wp[8];
            float4 w3 = *(const float4*)&wp[12];
#pragma unroll
            for (int q = 0; q < 4; ++q) {
                float v = __shfl(h2[q][r], l, 64);
                e[q][0]  = fmaf(w0.x, v, e[q][0]);
                e[q][1]  = fmaf(w0.y, v, e[q][1]);
                e[q][2]  = fmaf(w0.z, v, e[q][2]);
                e[q][3]  = fmaf(w0.w, v, e[q][3]);
                e[q][4]  = fmaf(w1.x, v, e[q][4]);
                e[q][5]  = fmaf(w1.y, v, e[q][5]);
                e[q][6]  = fmaf(w1.z, v, e[q][6]);
                e[q][7]  = fmaf(w1.w, v, e[q][7]);
                e[q][8]  = fmaf(w2.x, v, e[q][8]);
                e[q][9]  = fmaf(w2.y, v, e[q][9]);
                e[q][10] = fmaf(w2.z, v, e[q][10]);
                e[q][11] = fmaf(w2.w, v, e[q][11]);
                e[q][12] = fmaf(w3.x, v, e[q][12]);
                e[q][13] = fmaf(w3.y, v, e[q][13]);
                e[q][14] = fmaf(w3.z, v, e[q][14]);
                e[q][15] = fmaf(w3.w, v, e[q][15]);
            }
        }
    }
#pragma unroll
    for (int u = 0; u < 16; ++u) {
        float m = fmaxf(fmaxf(e[0][u], e[1][u]), fmaxf(e[2][u], e[3][u]));
        atomicMax(&g[b * 1024 + lane * 16 + u], mapf(m));
    }
}

// ---------- MLP4: 1024 -> 512 (relu) -> 512; round-4 version (UNCHANGED) ----------

__global__ __launch_bounds__(512) void mlp4_kernel(const unsigned* __restrict__ g,
                                                   const float* __restrict__ W0, const float* __restrict__ B0,
                                                   const float* __restrict__ W1, const float* __restrict__ B1,
                                                   float* __restrict__ out) {
    int b = blockIdx.x;
    int c = threadIdx.x;
    __shared__ float h[512];
    float a0 = B0[c], a1 = 0.f, a2 = 0.f, a3 = 0.f;
    for (int k = 0; k < 1024; k += 4) {
        float v0 = unmapf(g[b * 1024 + k]);
        float v1 = unmapf(g[b * 1024 + k + 1]);
        float v2 = unmapf(g[b * 1024 + k + 2]);
        float v3 = unmapf(g[b * 1024 + k + 3]);
        a0 = fmaf(v0, W0[k * 512 + c], a0);
        a1 = fmaf(v1, W0[(k + 1) * 512 + c], a1);
        a2 = fmaf(v2, W0[(k + 2) * 512 + c], a2);
        a3 = fmaf(v3, W0[(k + 3) * 512 + c], a3);
    }
    h[c] = fmaxf((a0 + a1) + (a2 + a3), 0.f);
    __syncthreads();
    float o0 = B1[c], o1 = 0.f, o2 = 0.f, o3 = 0.f;
    for (int k = 0; k < 512; k += 4) {
        o0 = fmaf(h[k], W1[k * 512 + c], o0);
        o1 = fmaf(h[k + 1], W1[(k + 1) * 512 + c], o1);
        o2 = fmaf(h[k + 2], W1[(k + 2) * 512 + c], o2);
        o3 = fmaf(h[k + 3], W1[(k + 3) * 512 + c], o3);
    }
    out[(size_t)b * 512 + c] = (o0 + o1) + (o2 + o3);
}

// ---------- launch ----------

extern "C" void kernel_launch(void* const* d_in, const int* in_sizes, int n_in,
                              void* d_out, int out_size, void* d_ws, size_t ws_size,
                              hipStream_t stream) {
    const float* pos = (const float*)d_in[0];  // [B*N, 6]
    const float* w1_0 = (const float*)d_in[3];
    const float* b1_0 = (const float*)d_in[4];
    const float* w1_1 = (const float*)d_in[5];
    const float* b1_1 = (const float*)d_in[6];
    const float* w1_2 = (const float*)d_in[7];
    const float* b1_2 = (const float*)d_in[8];
    const float* w2_0 = (const float*)d_in[9];
    const float* b2_0 = (const float*)d_in[10];
    const float* w2_1 = (const float*)d_in[11];
    const float* b2_1 = (const float*)d_in[12];
    const float* w2_2 = (const float*)d_in[13];
    const float* b2_2 = (const float*)d_in[14];
    const float* w3_0 = (const float*)d_in[15];
    const float* b3_0 = (const float*)d_in[16];
    const float* w3_1 = (const float*)d_in[17];
    const float* b3_1 = (const float*)d_in[18];
    const float* w3_2 = (const float*)d_in[19];
    const float* b3_2 = (const float*)d_in[20];
    const float* w4_0 = (const float*)d_in[21];
    const float* b4_0 = (const float*)d_in[22];
    const float* w4_1 = (const float*)d_in[23];
    const float* b4_1 = (const float*)d_in[24];
    float* out = (float*)d_out;

    char* ws = (char*)d_ws;
    size_t off = 0;
    float* pos1 = (float*)(ws + off);    off += (size_t)B_ * NS1_ * 6 * 4;
    float* pos2 = (float*)(ws + off);    off += (size_t)B_ * NS2_ * 6 * 4;
    float* x1 = (float*)(ws + off);      off += (size_t)B_ * NS1_ * 128 * 4;
    int* nbr2 = (int*)(ws + off);        off += (size_t)B_ * NS2_ * K_ * 4;
    int* cnt2 = (int*)(ws + off);        off += (size_t)B_ * NS2_ * 4;
    unsigned* g = (unsigned*)(ws + off); off += (size_t)B_ * 1024 * 4;
    unsigned* flags = (unsigned*)(ws + off); off += 64 * 4;
    // flags[0..7]=pos1 ready, flags[8..15]=pos2 ready, flags[48]=producers-done count

    const float r2_1 = (float)(0.2 * 0.2);
    const float r2_2 = (float)(0.4 * 0.4);

    hipMemsetAsync(flags, 0, 64 * 4, stream);

    // 1. fps1 -> {ball1+sa1, fps2, ball2} overlapped + clock-keeper spinners
    stage12_kernel<<<256, 256, 0, stream>>>(pos, pos1, pos2, x1, nbr2, cnt2, g, flags,
                                            w1_0, b1_0, w1_1, b1_1, w1_2, b1_2,
                                            r2_1, r2_2);
    // 2. sa2 + mlp3 fused (x2 via LDS)
    sa2_mlp3_kernel<<<(B_ * NS2_) / 16, 256, 0, stream>>>(pos1, pos2, nbr2, cnt2, x1,
                                                          w2_0, b2_0, w2_1, b2_1, w2_2, b2_2,
                                                          w3_0, b3_0, w3_1, b3_1, w3_2, b3_2, g);
    // 3. mlp4
    mlp4_kernel<<<B_, 512, 0, stream>>>(g, w4_0, b4_0, w4_1, b4_1, out);
}